// Round 1
// baseline (169.136 us; speedup 1.0000x reference)
//
#include <hip/hip_runtime.h>

#define OD 26
#define OH 122
#define OW 122
#define GS (128*128)
#define NOUT (OD*OH*OW)

// Stage 0: domain kernel dk[27] = relu(conv(relu(conv(dn,dw0)+db0),dw1)+db1)
// dn = domain_neighbor[1:8,1:8,1:8] (9x9x9 input). Voxel-independent -> once per launch.
__global__ void compute_dk_kernel(const float* __restrict__ dn,
                                  const float* __restrict__ dw0, const float* __restrict__ db0,
                                  const float* __restrict__ dw1, const float* __restrict__ db1,
                                  float* __restrict__ dk_out) {
    __shared__ float d0[125];
    int t = threadIdx.x;
    if (t < 125) {
        int tz = t / 25, ty = (t / 5) % 5, tx = t % 5;
        float acc = db0[0];
        #pragma unroll
        for (int kz = 0; kz < 3; ++kz)
            #pragma unroll
            for (int ky = 0; ky < 3; ++ky)
                #pragma unroll
                for (int kx = 0; kx < 3; ++kx)
                    acc += dw0[kz*9 + ky*3 + kx] *
                           dn[(1+tz+kz)*81 + (1+ty+ky)*9 + (1+tx+kx)];
        d0[t] = fmaxf(acc, 0.0f);
    }
    __syncthreads();
    if (t < 27) {
        int rz = t / 9, ry = (t / 3) % 3, rx = t % 3;
        float acc = db1[0];
        #pragma unroll
        for (int kz = 0; kz < 3; ++kz)
            #pragma unroll
            for (int ky = 0; ky < 3; ++ky)
                #pragma unroll
                for (int kx = 0; kx < 3; ++kx)
                    acc += dw1[kz*9 + ky*3 + kx] * d0[(rz+kz)*25 + (ry+ky)*5 + (rx+kx)];
        dk_out[t] = fmaxf(acc, 0.0f);
    }
}

// Main kernel: one thread per output voxel.
__global__ __launch_bounds__(256) void jbf_main_kernel(
        const float* __restrict__ x, const float* __restrict__ guide,
        const float* __restrict__ rw0p, const float* __restrict__ rb0p,
        const float* __restrict__ rw1p, const float* __restrict__ rb1p,
        const float* __restrict__ dkp, float* __restrict__ out) {
    int idx = blockIdx.x * blockDim.x + threadIdx.x;
    if (idx >= NOUT) return;
    int x0 = idx % OW;
    int y0 = (idx / OW) % OH;
    int z0 = idx / (OW * OH);

    // Wave-uniform weights (compiler should scalarize these loads).
    float rw0[27], rw1[27], dkv[27];
    #pragma unroll
    for (int i = 0; i < 27; ++i) { rw0[i] = rw0p[i]; rw1[i] = rw1p[i]; dkv[i] = dkp[i]; }
    const float rb0 = rb0p[0], rb1 = rb1p[0];

    const float gc = guide[(z0+3)*GS + (y0+3)*128 + (x0+3)];

    // conv1: t0[5][5][5] accumulated slice-by-slice over the 7 guide z-slices.
    float t0[125];
    #pragma unroll
    for (int i = 0; i < 125; ++i) t0[i] = rb0;

    #pragma unroll
    for (int gz = 0; gz < 7; ++gz) {
        float a[49];
        const float* gp = guide + (z0+gz)*GS + y0*128 + x0;
        #pragma unroll
        for (int gy = 0; gy < 7; ++gy)
            #pragma unroll
            for (int gx = 0; gx < 7; ++gx)
                a[gy*7 + gx] = fabsf(gp[gy*128 + gx] - gc);
        #pragma unroll
        for (int kz = 0; kz < 3; ++kz) {
            const int tz = gz - kz;
            if (tz < 0 || tz > 4) continue;   // compile-time folded
            #pragma unroll
            for (int ty = 0; ty < 5; ++ty)
                #pragma unroll
                for (int ky = 0; ky < 3; ++ky)
                    #pragma unroll
                    for (int tx = 0; tx < 5; ++tx)
                        #pragma unroll
                        for (int kx = 0; kx < 3; ++kx)
                            t0[tz*25 + ty*5 + tx] +=
                                rw0[kz*9 + ky*3 + kx] * a[(ty+ky)*7 + (tx+kx)];
        }
    }
    #pragma unroll
    for (int i = 0; i < 125; ++i) t0[i] = fmaxf(t0[i], 0.0f);

    // conv2 fused with weighting + reduction (rk never materialized).
    float num = 0.0f, den = 0.0f;
    #pragma unroll
    for (int rz = 0; rz < 3; ++rz)
        #pragma unroll
        for (int ry = 0; ry < 3; ++ry)
            #pragma unroll
            for (int rx = 0; rx < 3; ++rx) {
                float acc = rb1;
                #pragma unroll
                for (int kz = 0; kz < 3; ++kz)
                    #pragma unroll
                    for (int ky = 0; ky < 3; ++ky)
                        #pragma unroll
                        for (int kx = 0; kx < 3; ++kx)
                            acc += rw1[kz*9 + ky*3 + kx] *
                                   t0[(rz+kz)*25 + (ry+ky)*5 + (rx+kx)];
                const float w = dkv[rz*9 + ry*3 + rx] * fmaxf(acc, 0.0f) + 1e-10f;
                den += w;
                num += w * x[(z0+2+rz)*GS + (y0+2+ry)*128 + (x0+2+rx)];
            }

    out[idx] = num / den;
}

extern "C" void kernel_launch(void* const* d_in, const int* in_sizes, int n_in,
                              void* d_out, int out_size, void* d_ws, size_t ws_size,
                              hipStream_t stream) {
    const float* x     = (const float*)d_in[0];
    const float* dn    = (const float*)d_in[1];
    const float* guide = (const float*)d_in[2];
    const float* rw0   = (const float*)d_in[3];
    const float* rb0   = (const float*)d_in[4];
    const float* rw1   = (const float*)d_in[5];
    const float* rb1   = (const float*)d_in[6];
    const float* dw0   = (const float*)d_in[7];
    const float* db0   = (const float*)d_in[8];
    const float* dw1   = (const float*)d_in[9];
    const float* db1   = (const float*)d_in[10];
    float* out = (float*)d_out;
    float* dk  = (float*)d_ws;   // 27 floats

    compute_dk_kernel<<<1, 128, 0, stream>>>(dn, dw0, db0, dw1, db1, dk);

    int nblk = (NOUT + 255) / 256;
    jbf_main_kernel<<<nblk, 256, 0, stream>>>(x, guide, rw0, rb0, rw1, rb1, dk, out);
}